// Round 13
// baseline (112.249 us; speedup 1.0000x reference)
//
#include <hip/hip_runtime.h>

// LogSignature depth-4, C=16, B=64, L=256, fp32.
// out per batch: [lvl1(16) | lvl2(256) | lvl3(4096) | lvl4(65536)] = 69904
//
// v14 = v10 (best k_scan: 43.7us) + readlane row delivery.
// Occupancy axis is fully mapped (R8/R10/R12: 8 waves/CU, 2/SIMD is optimal);
// the remaining stall is the 16 wave-uniform row ds_read_b128 per 4-step
// group (73% of DS instrs). Rows are wave-uniform -> fetch the whole 4-row
// block with ONE ds_read_b32 (lane l reads float l of Lp[t*16..t*16+63];
// 64 consecutive floats = 2 lanes/bank = conflict-free), then deliver dv[d]
// via v_readlane (VALU pipe, SGPR operand feeds v_fmac directly).
// DS/group: 22 -> 7 (DS/CU ~28 -> ~8.5us); VALU +16 readlane/step (~25us/SIMD,
// now the binding pipe). Row register ping-pongs one group ahead (final
// overrun lands in Lc, in-bounds).
// k_scan: block (j,a), 128 threads = {h(1b)|b(4b)|c0(2b)}, 2 h-waves; thread
//   owns c-quad {c0,c0+4,c0+8,c0+12} (A=64). Streams from Lc [i][260]
//   (proven conflict-lite); step 255 zero-padded. Epilogue: A4+B4 merged in
//   slot-65 LDS layout, one coalesced 16KB write.
// k_log: v4's single-stage 2-chunk Chen merge + log correction (proven).
//
// ws (floats): sigA [64][4368] | sigB [64][4368]  (~2.2 MB)

#define NC 16
#define NL 256
#define NB 64
#define OUTB 69904
#define SIG123 4368
#define OFF_L2 16
#define OFF_L3 272
#define OFF_L4 4368
#define LCS 260  // padded component-major stride

#define SIGA_OFF 0
#define SIGB_OFF (NB * SIG123)

__device__ __forceinline__ float rl(float v, int lane) {
    return __int_as_float(__builtin_amdgcn_readlane(__float_as_int(v), lane));
}

__global__ __launch_bounds__(128, 2) void k_scan(const float* __restrict__ path,
                                                 float* __restrict__ out,
                                                 float* __restrict__ sigA,
                                                 float* __restrict__ sigB) {
    const int bid = blockIdx.x;
    const int j = bid >> 4;
    const int a = bid & 15;
    const int tid = threadIdx.x;
    const int h = tid >> 6;          // time chunk: 0 -> [0,128), 1 -> [128,256)
    const int b = (tid >> 2) & 15;
    const int c0 = tid & 3;          // owns c = c0, c0+4, c0+8, c0+12
    const int lane = tid & 63;

    __shared__ float Lp[NL * NC];    // time-major diffs (in place over path)
    __shared__ float Lc[NC * LCS];   // component-major diffs; reused as slot-65 merge buf

    // ---- stage path[j] (16 KB, coalesced; 8 float4 per thread) ----
    const float* pj = path + (size_t)j * NL * NC;
#pragma unroll
    for (int k = 0; k < 8; ++k) {
        const int f = tid + k * 128;
        *(float4*)&Lp[f * 4] = *(const float4*)&pj[f * 4];
    }
    __syncthreads();

    // ---- diffs; step 255 zero-padded (exact identity step) ----
    float4 dif[8];
#pragma unroll
    for (int k = 0; k < 8; ++k) {
        const int f = tid + k * 128;  // float4 index 0..1023
        if (f < 1020) {
            const float4 x0 = *(const float4*)&Lp[f * 4];
            const float4 x1 = *(const float4*)&Lp[f * 4 + 16];
            dif[k] = make_float4(x1.x - x0.x, x1.y - x0.y, x1.z - x0.z, x1.w - x0.w);
        } else {
            dif[k] = make_float4(0.f, 0.f, 0.f, 0.f);
        }
    }
    __syncthreads();
#pragma unroll
    for (int k = 0; k < 8; ++k) {
        const int f = tid + k * 128;
        *(float4*)&Lp[f * 4] = dif[k];
        const int t = f >> 2;            // time index 0..255
        const int i0 = 4 * (f & 3);      // component base
        Lc[(i0 + 0) * LCS + t] = dif[k].x;
        Lc[(i0 + 1) * LCS + t] = dif[k].y;
        Lc[(i0 + 2) * LCS + t] = dif[k].z;
        Lc[(i0 + 3) * LCS + t] = dif[k].w;
    }
    __syncthreads();

    // ---- chunk-local scan: 128 steps, c-quad accumulators ----
    float s4q[4][16];
#pragma unroll
    for (int m = 0; m < 4; ++m)
#pragma unroll
        for (int d = 0; d < 16; ++d) s4q[m][d] = 0.f;
    float s3q[4] = {0.f, 0.f, 0.f, 0.f};
    float s2ab = 0.f, s1a = 0.f;

    int t = h * 128;
    // row block (4 rows = 64 floats) lives wave-wide: lane l holds float l.
    float rowA = Lp[t * NC + lane];
    for (int it = 0; it < 32; ++it, t += 4) {
        const float4 va = *(const float4*)(Lc + a * LCS + t);    // broadcast
        const float4 vb = *(const float4*)(Lc + b * LCS + t);
        const float4 vc0 = *(const float4*)(Lc + c0 * LCS + t);
        const float4 vc1 = *(const float4*)(Lc + (c0 + 4) * LCS + t);
        const float4 vc2 = *(const float4*)(Lc + (c0 + 8) * LCS + t);
        const float4 vc3 = *(const float4*)(Lc + (c0 + 12) * LCS + t);
        // prefetch next group's rows (final overrun lands in Lc, in-bounds)
        const float rowB = Lp[(t + 4) * NC + lane];
#pragma unroll
        for (int u = 0; u < 4; ++u) {
            const float dxa = (u == 0) ? va.x : (u == 1) ? va.y : (u == 2) ? va.z : va.w;
            const float dxb = (u == 0) ? vb.x : (u == 1) ? vb.y : (u == 2) ? vb.z : vb.w;
            const float d0 = (u == 0) ? vc0.x : (u == 1) ? vc0.y : (u == 2) ? vc0.z : vc0.w;
            const float d1 = (u == 0) ? vc1.x : (u == 1) ? vc1.y : (u == 2) ? vc1.z : vc1.w;
            const float d2 = (u == 0) ? vc2.x : (u == 1) ? vc2.y : (u == 2) ? vc2.z : vc2.w;
            const float d3 = (u == 0) ? vc3.x : (u == 1) ? vc3.y : (u == 2) ? vc3.z : vc3.w;

            const float P = dxb * s1a;
            const float Q = dxb * dxa;
            const float pre4 = fmaf(1.f / 6.f, P, fmaf(1.f / 24.f, Q, 0.5f * s2ab));
            const float U = fmaf(0.5f, P, fmaf(1.f / 6.f, Q, s2ab));
            const float T0 = fmaf(d0, pre4, s3q[0]);
            const float T1 = fmaf(d1, pre4, s3q[1]);
            const float T2 = fmaf(d2, pre4, s3q[2]);
            const float T3 = fmaf(d3, pre4, s3q[3]);
#pragma unroll
            for (int d = 0; d < 16; ++d) {
                const float dv = rl(rowA, u * 16 + d);  // wave-uniform row elem
                s4q[0][d] = fmaf(dv, T0, s4q[0][d]);
                s4q[1][d] = fmaf(dv, T1, s4q[1][d]);
                s4q[2][d] = fmaf(dv, T2, s4q[2][d]);
                s4q[3][d] = fmaf(dv, T3, s4q[3][d]);
            }
            s3q[0] = fmaf(d0, U, s3q[0]);
            s3q[1] = fmaf(d1, U, s3q[1]);
            s3q[2] = fmaf(d2, U, s3q[2]);
            s3q[3] = fmaf(d3, U, s3q[3]);
            s2ab = fmaf(dxb, fmaf(0.5f, dxa, s1a), s2ab);
            s1a += dxa;
        }
        rowA = rowB;
    }

    // ---- epilogue: merge A4+B4 in slot-65 LDS layout (conflict-free) ----
    // slot = b*4 + c0 (0..63); within slot: m*16 + d (m = c>>2). Lc reused.
    __syncthreads();
    float* sl = Lc + (size_t)(b * 4 + c0) * 65;
    if (h == 0) {
#pragma unroll
        for (int m = 0; m < 4; ++m)
#pragma unroll
            for (int q = 0; q < 4; ++q)
                *(float4*)&sl[m * 16 + q * 4] =
                    make_float4(s4q[m][4 * q], s4q[m][4 * q + 1],
                                s4q[m][4 * q + 2], s4q[m][4 * q + 3]);
    }
    __syncthreads();
    if (h == 1) {
#pragma unroll
        for (int m = 0; m < 4; ++m)
#pragma unroll
            for (int q = 0; q < 4; ++q) {
                float4 v = *(const float4*)&sl[m * 16 + q * 4];
                v.x += s4q[m][4 * q];
                v.y += s4q[m][4 * q + 1];
                v.z += s4q[m][4 * q + 2];
                v.w += s4q[m][4 * q + 3];
                *(float4*)&sl[m * 16 + q * 4] = v;
            }
    }
    __syncthreads();
    {
        float* o4 = out + (size_t)j * OUTB + OFF_L4 + a * 4096;
#pragma unroll
        for (int k = 0; k < 8; ++k) {
            const int f = tid + k * 128;  // float4 index 0..1023
            const int m0 = f * 4;         // element offset: bb*256 + cc*16 + dd
            const int bb = m0 >> 8;
            const int cc = (m0 >> 4) & 15;
            const int dd = m0 & 15;
            const int src = (bb * 4 + (cc & 3)) * 65 + (cc >> 2) * 16 + dd;
            *(float4*)(o4 + m0) = *(const float4*)&Lc[src];
        }
    }

    // ---- levels 1-3 of this thread's chunk ----
    float* sg = (h ? sigB : sigA) + (size_t)j * SIG123;
#pragma unroll
    for (int m = 0; m < 4; ++m)
        sg[OFF_L3 + (a * 16 + b) * 16 + c0 + 4 * m] = s3q[m];
    if (c0 == 0) sg[OFF_L2 + a * 16 + b] = s2ab;
    if ((tid & 63) == 0) sg[a] = s1a;
}

// Chen cross-terms (S4 = [A4+B4] + A1(x)B3 + A2(x)B2 + A3(x)B1) + log
// correction. Block (j,a). Merged S1/S2/S3 in LDS (~20 KB); B3 from global
// (L2-resident). v4-proven.
__global__ __launch_bounds__(256) void k_log(const float* __restrict__ sigA,
                                             const float* __restrict__ sigB,
                                             float* __restrict__ out) {
    const int bid = blockIdx.x;
    const int j = bid >> 4;
    const int a = bid & 15;
    const int tid = threadIdx.x;
    const int q = tid >> 4;
    const int r = tid & 15;

    const float* A = sigA + (size_t)j * SIG123;
    const float* Bp = sigB + (size_t)j * SIG123;

    __shared__ float S1m[16], B1s[16], A2s[16];
    __shared__ float S2m[256], B2s[256], A3s[256];
    __shared__ float S3m[4096];

    const float b1r = Bp[r];             // B1[r]
    const float b2t = Bp[OFF_L2 + tid];  // B2[q,r]

    if (tid < 16) {
        const float bb = Bp[tid];
        B1s[tid] = bb;
        S1m[tid] = A[tid] + bb;               // S1 = A1 + B1
        A2s[tid] = A[OFF_L2 + a * 16 + tid];  // A2[a,:]
    }
    B2s[tid] = b2t;
    S2m[tid] = A[OFF_L2 + tid] + b2t + A[q] * b1r;  // S2 = A2 + B2 + A1(x)B1
    A3s[tid] = A[OFF_L3 + a * 256 + tid];           // A3[a,:,:]
#pragma unroll
    for (int k = 0; k < 16; ++k) {  // S3[p,q,r] = A3 + B3 + A1[p]B2[qr] + A2[pq]B1[r]
        const int m = k * 256 + tid;
        S3m[m] = A[OFF_L3 + m] + Bp[OFF_L3 + m] + A[k] * b2t + A[OFF_L2 + k * 16 + q] * b1r;
    }
    __syncthreads();

    const float s1a = S1m[a];
    const float A1a = A[a];
    float* outj = out + (size_t)j * OUTB;
    float* o4 = outj + OFF_L4 + a * 4096;
    const float Ac = -0.5f * s1a;

#pragma unroll
    for (int k = 0; k < 4; ++k) {
        const int f = tid + k * 256;
        const int m0 = f * 4;  // element offset: bb*256 + cc*16 + d0
        const int bb = m0 >> 8;
        const int cc = (m0 >> 4) & 15;
        const float s1b = S1m[bb], s1c = S1m[cc];
        const float s2ab = S2m[a * 16 + bb];
        const float s2bc = S2m[bb * 16 + cc];
        const float s3abc = S3m[a * 256 + (m0 >> 4)];  // merged S3[a,b,c]
        const float a3x = A3s[m0 >> 4];                // A3[a,b,c]
        const float a2x = A2s[bb];                     // A2[a,b]

        const float4 a4 = *(const float4*)(o4 + m0);            // A4+B4
        const float4 b3v = *(const float4*)(Bp + OFF_L3 + m0);  // B3[b,c,d..] (L2)
        const float4 b2v = *(const float4*)(&B2s[m0 & 255]);
        const float4 b1v = *(const float4*)(&B1s[m0 & 15]);
        const float4 v3 = *(const float4*)(&S3m[m0]);
        const float4 v2 = *(const float4*)(&S2m[m0 & 255]);
        const float4 v1 = *(const float4*)(&S1m[m0 & 15]);

        const float Bv = fmaf((1.f / 3.f) * s1a, s1b, -0.5f * s2ab);
        const float Cv = -0.5f * s3abc + (1.f / 3.f) * fmaf(s1a, s2bc, s2ab * s1c)
                         - 0.25f * s1a * s1b * s1c;
        float4 rv;
        // merged S4 = (A4+B4) + A1[a]B3[bcd] + A2[ab]B2[cd] + A3[abc]B1[d]
        rv.x = a4.x + fmaf(A1a, b3v.x, fmaf(a2x, b2v.x, a3x * b1v.x));
        rv.y = a4.y + fmaf(A1a, b3v.y, fmaf(a2x, b2v.y, a3x * b1v.y));
        rv.z = a4.z + fmaf(A1a, b3v.z, fmaf(a2x, b2v.z, a3x * b1v.z));
        rv.w = a4.w + fmaf(A1a, b3v.w, fmaf(a2x, b2v.w, a3x * b1v.w));
        // log correction
        rv.x = fmaf(Ac, v3.x, rv.x) + fmaf(Bv, v2.x, Cv * v1.x);
        rv.y = fmaf(Ac, v3.y, rv.y) + fmaf(Bv, v2.y, Cv * v1.y);
        rv.z = fmaf(Ac, v3.z, rv.z) + fmaf(Bv, v2.z, Cv * v1.z);
        rv.w = fmaf(Ac, v3.w, rv.w) + fmaf(Bv, v2.w, Cv * v1.w);
        *(float4*)(o4 + m0) = rv;
    }

    // level 3 (coalesced)
    {
        const float s1b = S1m[q], s1c = S1m[r];
        const float s2ab = S2m[a * 16 + q];
        const float s2bc = S2m[q * 16 + r];
        const float s3abc = S3m[a * 256 + tid];
        const float r3 = s3abc - 0.5f * fmaf(s1a, s2bc, s2ab * s1c)
                         + (1.f / 3.f) * s1a * s1b * s1c;
        outj[OFF_L3 + a * 256 + tid] = r3;
    }
    // level 2
    if (tid < 16) outj[OFF_L2 + a * 16 + tid] = fmaf(-0.5f * s1a, S1m[tid], S2m[a * 16 + tid]);
    // level 1
    if (tid == 0) outj[a] = s1a;
}

extern "C" void kernel_launch(void* const* d_in, const int* in_sizes, int n_in,
                              void* d_out, int out_size, void* d_ws, size_t ws_size,
                              hipStream_t stream) {
    const float* path = (const float*)d_in[0];
    float* out = (float*)d_out;
    float* ws = (float*)d_ws;
    float* sigA = ws + SIGA_OFF;
    float* sigB = ws + SIGB_OFF;

    k_scan<<<NB * 16, 128, 0, stream>>>(path, out, sigA, sigB);
    k_log<<<NB * 16, 256, 0, stream>>>(sigA, sigB, out);
}

// Round 14
// 107.050 us; speedup vs baseline: 1.0486x; 1.0486x over previous
//
#include <hip/hip_runtime.h>

// LogSignature depth-4, C=16, B=64, L=256, fp32.
// out per batch: [lvl1(16) | lvl2(256) | lvl3(4096) | lvl4(65536)] = 69904
//
// FINAL = v10 (best measured: 105.9us total, k_scan 43.7us @ R9).
// Session map (R0->R13): 124.9 -> 105.9 via (1) in-block Chen time-split,
// (2) c-quad accumulators (A=64/thread, halving wave-uniform row reads),
// (3) slot-65 conflict-free epilogue, (4) single-stage 2-chunk Chen merge
// k_log. Refuted axes: occupancy x2 / /2 (null / -14%), VMEM or readlane
// row delivery (-70% / -13%), inline-asm pk_fma (-13%), LDS compaction +
// XOR swizzle (null), grid-sync fusion (-3x), 3-stage merge (-35us).
// Remaining gap to the ~28us DS floor is a dependent-load latency plateau
// (no pipe saturated: VALU ~49%, DS ~60%, HBM 6%) that resisted six
// counter-motivated attacks; ~52us of dur_us is fixed harness overhead.
//
// k_scan: block (j,a), 128 threads = {h(1b)|b(4b)|c0(2b)}, 2 waves. Thread
//   owns a c-QUAD {c0,c0+4,c0+8,c0+12}; 2-way in-block time split (Chen),
//   step 255 zero-padded (uniform 32x4 loop). Rows via uniform ds_read_b128
//   broadcast from Lp; streams via conflict-lite b128 from Lc (stride 260).
//   Epilogue: A4+B4 merged in slot-65 LDS layout, one coalesced 16KB write.
// k_log: Chen cross-terms (S4 = [A4+B4] + A1xB3 + A2xB2 + A3xB1) + log
//   correction; merged S1/S2/S3 in LDS; B3 from L2-resident global.
//
// ws (floats): sigA [64][4368] | sigB [64][4368]  (~2.2 MB)

#define NC 16
#define NL 256
#define NB 64
#define OUTB 69904
#define SIG123 4368
#define OFF_L2 16
#define OFF_L3 272
#define OFF_L4 4368
#define LCS 260  // padded component-major stride

#define SIGA_OFF 0
#define SIGB_OFF (NB * SIG123)

typedef float v2f __attribute__((ext_vector_type(2)));

__global__ __launch_bounds__(128, 2) void k_scan(const float* __restrict__ path,
                                                 float* __restrict__ out,
                                                 float* __restrict__ sigA,
                                                 float* __restrict__ sigB) {
    const int bid = blockIdx.x;
    const int j = bid >> 4;
    const int a = bid & 15;
    const int tid = threadIdx.x;
    const int h = tid >> 6;          // time chunk: 0 -> [0,128), 1 -> [128,256)
    const int b = (tid >> 2) & 15;
    const int c0 = tid & 3;          // owns c = c0, c0+4, c0+8, c0+12

    __shared__ float Lp[NL * NC];    // time-major diffs (in place over path)
    __shared__ float Lc[NC * LCS];   // component-major diffs; reused as slot-65 merge buf

    // ---- stage path[j] (16 KB, coalesced; 8 float4 per thread) ----
    const float* pj = path + (size_t)j * NL * NC;
#pragma unroll
    for (int k = 0; k < 8; ++k) {
        const int f = tid + k * 128;
        *(float4*)&Lp[f * 4] = *(const float4*)&pj[f * 4];
    }
    __syncthreads();

    // ---- diffs; step 255 zero-padded (exact identity step) ----
    float4 dif[8];
#pragma unroll
    for (int k = 0; k < 8; ++k) {
        const int f = tid + k * 128;  // float4 index 0..1023
        if (f < 1020) {
            const float4 x0 = *(const float4*)&Lp[f * 4];
            const float4 x1 = *(const float4*)&Lp[f * 4 + 16];
            dif[k] = make_float4(x1.x - x0.x, x1.y - x0.y, x1.z - x0.z, x1.w - x0.w);
        } else {
            dif[k] = make_float4(0.f, 0.f, 0.f, 0.f);
        }
    }
    __syncthreads();
#pragma unroll
    for (int k = 0; k < 8; ++k) {
        const int f = tid + k * 128;
        *(float4*)&Lp[f * 4] = dif[k];
        const int t = f >> 2;            // time index 0..255
        const int i0 = 4 * (f & 3);      // component base
        Lc[(i0 + 0) * LCS + t] = dif[k].x;
        Lc[(i0 + 1) * LCS + t] = dif[k].y;
        Lc[(i0 + 2) * LCS + t] = dif[k].z;
        Lc[(i0 + 3) * LCS + t] = dif[k].w;
    }
    __syncthreads();

    // ---- chunk-local scan: 128 steps, c-quad accumulators ----
    v2f s4q[4][8];
#pragma unroll
    for (int m = 0; m < 4; ++m)
#pragma unroll
        for (int d = 0; d < 8; ++d) s4q[m][d] = (v2f){0.f, 0.f};
    float s3q[4] = {0.f, 0.f, 0.f, 0.f};
    float s2ab = 0.f, s1a = 0.f;

    auto body = [&](const float4& q0, const float4& q1, const float4& q2,
                    const float4& q3, float dxa, float dxb, float dc0, float dc1,
                    float dc2, float dc3) {
        const float P = dxb * s1a;
        const float Q = dxb * dxa;
        const float pre4 = fmaf(1.f / 6.f, P, fmaf(1.f / 24.f, Q, 0.5f * s2ab));
        const float U = fmaf(0.5f, P, fmaf(1.f / 6.f, Q, s2ab));
        const float T0 = fmaf(dc0, pre4, s3q[0]);
        const float T1 = fmaf(dc1, pre4, s3q[1]);
        const float T2 = fmaf(dc2, pre4, s3q[2]);
        const float T3 = fmaf(dc3, pre4, s3q[3]);
        const v2f dv2[8] = {{q0.x, q0.y}, {q0.z, q0.w}, {q1.x, q1.y}, {q1.z, q1.w},
                            {q2.x, q2.y}, {q2.z, q2.w}, {q3.x, q3.y}, {q3.z, q3.w}};
        const v2f Tv0 = {T0, T0}, Tv1 = {T1, T1}, Tv2 = {T2, T2}, Tv3 = {T3, T3};
#pragma unroll
        for (int d = 0; d < 8; ++d) {
            s4q[0][d] = __builtin_elementwise_fma(dv2[d], Tv0, s4q[0][d]);
            s4q[1][d] = __builtin_elementwise_fma(dv2[d], Tv1, s4q[1][d]);
            s4q[2][d] = __builtin_elementwise_fma(dv2[d], Tv2, s4q[2][d]);
            s4q[3][d] = __builtin_elementwise_fma(dv2[d], Tv3, s4q[3][d]);
        }
        s3q[0] = fmaf(dc0, U, s3q[0]);
        s3q[1] = fmaf(dc1, U, s3q[1]);
        s3q[2] = fmaf(dc2, U, s3q[2]);
        s3q[3] = fmaf(dc3, U, s3q[3]);
        s2ab = fmaf(dxb, fmaf(0.5f, dxa, s1a), s2ab);
        s1a += dxa;
    };

    int t = h * 128;
    for (int it = 0; it < 32; ++it, t += 4) {
        const float4 va = *(const float4*)(Lc + a * LCS + t);         // broadcast
        const float4 vb = *(const float4*)(Lc + b * LCS + t);
        const float4 vc0 = *(const float4*)(Lc + c0 * LCS + t);
        const float4 vc1 = *(const float4*)(Lc + (c0 + 4) * LCS + t);
        const float4 vc2 = *(const float4*)(Lc + (c0 + 8) * LCS + t);
        const float4 vc3 = *(const float4*)(Lc + (c0 + 12) * LCS + t);
#pragma unroll
        for (int u = 0; u < 4; ++u) {
            const float* r = Lp + (t + u) * NC;   // uniform row, b128 broadcast
            const float4 q0 = *(const float4*)(r);
            const float4 q1 = *(const float4*)(r + 4);
            const float4 q2 = *(const float4*)(r + 8);
            const float4 q3 = *(const float4*)(r + 12);
            const float dxa = (u == 0) ? va.x : (u == 1) ? va.y : (u == 2) ? va.z : va.w;
            const float dxb = (u == 0) ? vb.x : (u == 1) ? vb.y : (u == 2) ? vb.z : vb.w;
            const float d0 = (u == 0) ? vc0.x : (u == 1) ? vc0.y : (u == 2) ? vc0.z : vc0.w;
            const float d1 = (u == 0) ? vc1.x : (u == 1) ? vc1.y : (u == 2) ? vc1.z : vc1.w;
            const float d2 = (u == 0) ? vc2.x : (u == 1) ? vc2.y : (u == 2) ? vc2.z : vc2.w;
            const float d3 = (u == 0) ? vc3.x : (u == 1) ? vc3.y : (u == 2) ? vc3.z : vc3.w;
            body(q0, q1, q2, q3, dxa, dxb, d0, d1, d2, d3);
        }
    }

    // ---- epilogue: merge A4+B4 in slot-65 LDS layout (conflict-free) ----
    // slot = b*4 + c0 (0..63); within slot: m*16 + d (m = c>>2). Lc reused.
    __syncthreads();
    float* sl = Lc + (size_t)(b * 4 + c0) * 65;
    if (h == 0) {
#pragma unroll
        for (int m = 0; m < 4; ++m)
#pragma unroll
            for (int q = 0; q < 4; ++q)
                *(float4*)&sl[m * 16 + q * 4] =
                    make_float4(s4q[m][2 * q].x, s4q[m][2 * q].y,
                                s4q[m][2 * q + 1].x, s4q[m][2 * q + 1].y);
    }
    __syncthreads();
    if (h == 1) {
#pragma unroll
        for (int m = 0; m < 4; ++m)
#pragma unroll
            for (int q = 0; q < 4; ++q) {
                float4 v = *(const float4*)&sl[m * 16 + q * 4];
                v.x += s4q[m][2 * q].x;
                v.y += s4q[m][2 * q].y;
                v.z += s4q[m][2 * q + 1].x;
                v.w += s4q[m][2 * q + 1].y;
                *(float4*)&sl[m * 16 + q * 4] = v;
            }
    }
    __syncthreads();
    {
        float* o4 = out + (size_t)j * OUTB + OFF_L4 + a * 4096;
#pragma unroll
        for (int k = 0; k < 8; ++k) {
            const int f = tid + k * 128;  // float4 index 0..1023
            const int m0 = f * 4;         // element offset: bb*256 + cc*16 + dd
            const int bb = m0 >> 8;
            const int cc = (m0 >> 4) & 15;
            const int dd = m0 & 15;
            const int src = (bb * 4 + (cc & 3)) * 65 + (cc >> 2) * 16 + dd;
            *(float4*)(o4 + m0) = *(const float4*)&Lc[src];
        }
    }

    // ---- levels 1-3 of this thread's chunk ----
    float* sg = (h ? sigB : sigA) + (size_t)j * SIG123;
#pragma unroll
    for (int m = 0; m < 4; ++m)
        sg[OFF_L3 + (a * 16 + b) * 16 + c0 + 4 * m] = s3q[m];
    if (c0 == 0) sg[OFF_L2 + a * 16 + b] = s2ab;
    if ((tid & 63) == 0) sg[a] = s1a;
}

// Chen cross-terms (S4 = [A4+B4] + A1(x)B3 + A2(x)B2 + A3(x)B1) + log
// correction. Block (j,a). Merged S1/S2/S3 in LDS (~20 KB); B3 from global
// (L2-resident).
__global__ __launch_bounds__(256) void k_log(const float* __restrict__ sigA,
                                             const float* __restrict__ sigB,
                                             float* __restrict__ out) {
    const int bid = blockIdx.x;
    const int j = bid >> 4;
    const int a = bid & 15;
    const int tid = threadIdx.x;
    const int q = tid >> 4;
    const int r = tid & 15;

    const float* A = sigA + (size_t)j * SIG123;
    const float* Bp = sigB + (size_t)j * SIG123;

    __shared__ float S1m[16], B1s[16], A2s[16];
    __shared__ float S2m[256], B2s[256], A3s[256];
    __shared__ float S3m[4096];

    const float b1r = Bp[r];             // B1[r]
    const float b2t = Bp[OFF_L2 + tid];  // B2[q,r]

    if (tid < 16) {
        const float bb = Bp[tid];
        B1s[tid] = bb;
        S1m[tid] = A[tid] + bb;               // S1 = A1 + B1
        A2s[tid] = A[OFF_L2 + a * 16 + tid];  // A2[a,:]
    }
    B2s[tid] = b2t;
    S2m[tid] = A[OFF_L2 + tid] + b2t + A[q] * b1r;  // S2 = A2 + B2 + A1(x)B1
    A3s[tid] = A[OFF_L3 + a * 256 + tid];           // A3[a,:,:]
#pragma unroll
    for (int k = 0; k < 16; ++k) {  // S3[p,q,r] = A3 + B3 + A1[p]B2[qr] + A2[pq]B1[r]
        const int m = k * 256 + tid;
        S3m[m] = A[OFF_L3 + m] + Bp[OFF_L3 + m] + A[k] * b2t + A[OFF_L2 + k * 16 + q] * b1r;
    }
    __syncthreads();

    const float s1a = S1m[a];
    const float A1a = A[a];
    float* outj = out + (size_t)j * OUTB;
    float* o4 = outj + OFF_L4 + a * 4096;
    const float Ac = -0.5f * s1a;

#pragma unroll
    for (int k = 0; k < 4; ++k) {
        const int f = tid + k * 256;
        const int m0 = f * 4;  // element offset: bb*256 + cc*16 + d0
        const int bb = m0 >> 8;
        const int cc = (m0 >> 4) & 15;
        const float s1b = S1m[bb], s1c = S1m[cc];
        const float s2ab = S2m[a * 16 + bb];
        const float s2bc = S2m[bb * 16 + cc];
        const float s3abc = S3m[a * 256 + (m0 >> 4)];  // merged S3[a,b,c]
        const float a3x = A3s[m0 >> 4];                // A3[a,b,c]
        const float a2x = A2s[bb];                     // A2[a,b]

        const float4 a4 = *(const float4*)(o4 + m0);            // A4+B4
        const float4 b3v = *(const float4*)(Bp + OFF_L3 + m0);  // B3[b,c,d..] (L2)
        const float4 b2v = *(const float4*)(&B2s[m0 & 255]);
        const float4 b1v = *(const float4*)(&B1s[m0 & 15]);
        const float4 v3 = *(const float4*)(&S3m[m0]);
        const float4 v2 = *(const float4*)(&S2m[m0 & 255]);
        const float4 v1 = *(const float4*)(&S1m[m0 & 15]);

        const float Bv = fmaf((1.f / 3.f) * s1a, s1b, -0.5f * s2ab);
        const float Cv = -0.5f * s3abc + (1.f / 3.f) * fmaf(s1a, s2bc, s2ab * s1c)
                         - 0.25f * s1a * s1b * s1c;
        float4 rv;
        // merged S4 = (A4+B4) + A1[a]B3[bcd] + A2[ab]B2[cd] + A3[abc]B1[d]
        rv.x = a4.x + fmaf(A1a, b3v.x, fmaf(a2x, b2v.x, a3x * b1v.x));
        rv.y = a4.y + fmaf(A1a, b3v.y, fmaf(a2x, b2v.y, a3x * b1v.y));
        rv.z = a4.z + fmaf(A1a, b3v.z, fmaf(a2x, b2v.z, a3x * b1v.z));
        rv.w = a4.w + fmaf(A1a, b3v.w, fmaf(a2x, b2v.w, a3x * b1v.w));
        // log correction
        rv.x = fmaf(Ac, v3.x, rv.x) + fmaf(Bv, v2.x, Cv * v1.x);
        rv.y = fmaf(Ac, v3.y, rv.y) + fmaf(Bv, v2.y, Cv * v1.y);
        rv.z = fmaf(Ac, v3.z, rv.z) + fmaf(Bv, v2.z, Cv * v1.z);
        rv.w = fmaf(Ac, v3.w, rv.w) + fmaf(Bv, v2.w, Cv * v1.w);
        *(float4*)(o4 + m0) = rv;
    }

    // level 3 (coalesced)
    {
        const float s1b = S1m[q], s1c = S1m[r];
        const float s2ab = S2m[a * 16 + q];
        const float s2bc = S2m[q * 16 + r];
        const float s3abc = S3m[a * 256 + tid];
        const float r3 = s3abc - 0.5f * fmaf(s1a, s2bc, s2ab * s1c)
                         + (1.f / 3.f) * s1a * s1b * s1c;
        outj[OFF_L3 + a * 256 + tid] = r3;
    }
    // level 2
    if (tid < 16) outj[OFF_L2 + a * 16 + tid] = fmaf(-0.5f * s1a, S1m[tid], S2m[a * 16 + tid]);
    // level 1
    if (tid == 0) outj[a] = s1a;
}

extern "C" void kernel_launch(void* const* d_in, const int* in_sizes, int n_in,
                              void* d_out, int out_size, void* d_ws, size_t ws_size,
                              hipStream_t stream) {
    const float* path = (const float*)d_in[0];
    float* out = (float*)d_out;
    float* ws = (float*)d_ws;
    float* sigA = ws + SIGA_OFF;
    float* sigB = ws + SIGB_OFF;

    k_scan<<<NB * 16, 128, 0, stream>>>(path, out, sigA, sigB);
    k_log<<<NB * 16, 256, 0, stream>>>(sigA, sigB, out);
}